// Round 5
// baseline (316.184 us; speedup 1.0000x reference)
//
#include <hip/hip_runtime.h>

#define NREL 3
#define NB    64            // buckets per push-list
#define CS    16            // ints per bucket counter (64 B line each)
#define CAP0  131072        // nodes needing h0  (expected ~45K)
#define CAP1  32768         // nodes needing h1  (hard bound 5000+CAPE2 < 22K)
#define CAPE1 131072        // layer-1 relevant edges (expected ~30K)
#define CAPE2 16384         // layer-2 relevant edges (expected ~10K)
#define BC0   (CAP0 / NB)   // 2048 (shift 11)
#define BC1   (CAP1 / NB)   // 512  (shift 9)
#define BCE1  (CAPE1 / NB)  // 2048 (shift 11)
#define BCE2  (CAPE2 / NB)  // 256  (shift 8)
// ctr: 4 lists x 64 buckets x 16 ints. list 0=nodes1, 1=nodes0, 2=elist1, 3=elist2
#define CTR(list, b) ((list) * NB * CS + (b) * CS)

__device__ __forceinline__ int bittest(const unsigned* bm, int n) {
    return (bm[n >> 5] >> (n & 31)) & 1u;
}

__device__ __forceinline__ void claim_node(int n, int* __restrict__ slot,
                                           int* __restrict__ nodes,
                                           int* __restrict__ ctr, int list,
                                           int bcap, int bucket) {
    if (atomicCAS(&slot[n], -1, -2) == -1) {
        int p = atomicAdd(&ctr[CTR(list, bucket)], 1);
        if (p < bcap) {
            int sl = bucket * bcap + p;
            nodes[sl] = n;
            atomicExch(&slot[n], sl);
        }
    }
}

// ---- per graph: mark last node, claim its h1/h0 slots ----
__global__ void mark_last_k(const int* __restrict__ ptr, int* __restrict__ inv_map,
                            unsigned* __restrict__ bitL, unsigned* __restrict__ bitN1,
                            int* __restrict__ slot1, int* __restrict__ slot0,
                            int* __restrict__ nodes1, int* __restrict__ nodes0,
                            int* __restrict__ ctr, int G) {
    int g = blockIdx.x * blockDim.x + threadIdx.x;
    if (g >= G) return;
    int bucket = g & (NB - 1);
    int last = ptr[g + 1] - 1;
    inv_map[last] = g;
    atomicOr(&bitL[last >> 5], 1u << (last & 31));
    atomicOr(&bitN1[last >> 5], 1u << (last & 31));
    claim_node(last, slot1, nodes1, ctr, 0, BC1, bucket);
    claim_node(last, slot0, nodes0, ctr, 1, BC0, bucket);
}

// ---- scan edges: dst is last node -> elist2; src joins need1 (+h0) ----
__global__ void edge_pass1_k(const int* __restrict__ src, const int* __restrict__ dst,
                             const unsigned* __restrict__ bitL, unsigned* __restrict__ bitN1,
                             int* __restrict__ slot1, int* __restrict__ slot0,
                             int* __restrict__ nodes1, int* __restrict__ nodes0,
                             int* __restrict__ elist2, int* __restrict__ ctr, int nE) {
    int t = blockIdx.x * blockDim.x + threadIdx.x;
    int bucket = (t >> 6) & (NB - 1);
    int e0 = t * 4;
    if (e0 >= nE) return;
    int d[4];
    int cnt = min(4, nE - e0);
    if (cnt == 4) { int4 v = *(const int4*)(dst + e0); d[0]=v.x; d[1]=v.y; d[2]=v.z; d[3]=v.w; }
    else for (int k = 0; k < cnt; k++) d[k] = dst[e0 + k];
#pragma unroll
    for (int k = 0; k < 4; k++) {
        if (k >= cnt) break;
        if (bittest(bitL, d[k])) {
            int e = e0 + k;
            int p = atomicAdd(&ctr[CTR(3, bucket)], 1);
            if (p < BCE2) elist2[bucket * BCE2 + p] = e;
            int s = src[e];
            atomicOr(&bitN1[s >> 5], 1u << (s & 31));
            claim_node(s, slot1, nodes1, ctr, 0, BC1, bucket);
            claim_node(s, slot0, nodes0, ctr, 1, BC0, bucket);
        }
    }
}

// ---- scan edges: dst in need1 -> elist1 + per-(slot,rel) counts; src joins h0 set ----
__global__ void edge_pass2_k(const int* __restrict__ src, const int* __restrict__ dst,
                             const int* __restrict__ et, const unsigned* __restrict__ bitN1,
                             const int* __restrict__ slot1, int* __restrict__ slot0,
                             int* __restrict__ nodes0, int* __restrict__ elist1,
                             float* __restrict__ cntc, int* __restrict__ ctr, int nE) {
    int t = blockIdx.x * blockDim.x + threadIdx.x;
    int bucket = (t >> 6) & (NB - 1);
    int e0 = t * 4;
    if (e0 >= nE) return;
    int d[4];
    int cnt = min(4, nE - e0);
    if (cnt == 4) { int4 v = *(const int4*)(dst + e0); d[0]=v.x; d[1]=v.y; d[2]=v.z; d[3]=v.w; }
    else for (int k = 0; k < cnt; k++) d[k] = dst[e0 + k];
#pragma unroll
    for (int k = 0; k < 4; k++) {
        if (k >= cnt) break;
        if (bittest(bitN1, d[k])) {
            int e = e0 + k;
            int s1 = slot1[d[k]];                 // hit path only (~3% of edges)
            if (s1 >= 0) {
                int p = atomicAdd(&ctr[CTR(2, bucket)], 1);
                if (p < BCE1) elist1[bucket * BCE1 + p] = e;
                atomicAdd(&cntc[s1 * 4 + et[e]], 1.0f);
                claim_node(src[e], slot0, nodes0, ctr, 1, BC0, bucket);
            }
        }
    }
}

// ---- counts -> reciprocals ----
__global__ void inv_k(float* __restrict__ cntc, int n) {
    int i = blockIdx.x * blockDim.x + threadIdx.x;
    if (i < n) cntc[i] = 1.0f / fmaxf(cntc[i], 1.0f);
}

// ---- embed + pre-linear + relu for claimed h0 slots ----
__global__ void h0_k(const int* __restrict__ x, const float* __restrict__ se,
                     const float* __restrict__ ce, const float* __restrict__ pw,
                     const float* __restrict__ pb, const int* __restrict__ nodes0,
                     const int* __restrict__ ctr, float* __restrict__ h0c) {
    __shared__ float s_se[128], s_ce[128], s_pw[512], s_pb[32];
    int t = threadIdx.x;
    if (t < 128) { s_se[t] = se[t]; s_ce[t] = ce[t]; }
    if (t < 32)  s_pb[t] = pb[t];
    for (int i = t; i < 512; i += 256) s_pw[i] = pw[i];
    __syncthreads();
    int lane = t & 63, f = lane & 31;
    int wv  = (blockIdx.x * blockDim.x + t) >> 6;
    int nwv = (gridDim.x * blockDim.x) >> 6;
    int b = wv & (NB - 1);
    int cb = min(ctr[CTR(1, b)], BC0);
    int step = (nwv >> 6) * 2;
    for (int i = (wv >> 6) * 2 + (lane >> 5); i < cb; i += step) {
        int p = b * BC0 + i;
        int n = nodes0[p];
        int x0 = x[n * 2], x1 = x[n * 2 + 1];
        float acc = s_pb[f];
#pragma unroll
        for (int k = 0; k < 8; k++) acc += s_se[x0 * 8 + k] * s_pw[k * 32 + f];
#pragma unroll
        for (int k = 0; k < 8; k++) acc += s_ce[x1 * 8 + k] * s_pw[(k + 8) * 32 + f];
        h0c[p * 32 + f] = fmaxf(acc, 0.0f);
    }
}

// ---- resolve layer-1 edges: flatten gather chain into packed records ----
__global__ void resolve1_k(const int* __restrict__ src, const int* __restrict__ dst,
                           const int* __restrict__ et, const int* __restrict__ elist1,
                           const int* __restrict__ slot0, const int* __restrict__ slot1,
                           const int* __restrict__ ctr, int2* __restrict__ rec1) {
    for (int idx = blockIdx.x * blockDim.x + threadIdx.x; idx < CAPE1;
         idx += gridDim.x * blockDim.x) {
        int b = idx >> 11, i = idx & (BCE1 - 1);
        if (i >= min(ctr[CTR(2, b)], BCE1)) continue;
        int e = elist1[idx];
        int s0 = slot0[src[e]];
        int s1 = slot1[dst[e]];
        int row = (s1 >= 0) ? (s1 * 4 + et[e]) : -1;
        rec1[idx] = make_int2(s0, row);
    }
}

// ---- accumulate raw h0 into per-(slot,rel) sums: chain depth 2 ----
__global__ void msg1_acc_k(const int2* __restrict__ rec1, const float* __restrict__ h0c,
                           float* __restrict__ aggm1, const int* __restrict__ ctr) {
    int t = threadIdx.x;
    int f = t & 31, half = (t >> 5) & 1;
    int wv  = (blockIdx.x * blockDim.x + t) >> 6;
    int nwv = (gridDim.x * blockDim.x) >> 6;
    int b = wv & (NB - 1);
    int cb = min(ctr[CTR(2, b)], BCE1);
    int step = (nwv >> 6) * 2;
    for (int i = (wv >> 6) * 2 + half; i < cb; i += step) {
        int j = b * BCE1 + i;
        int2 rc = rec1[j];
        if (rc.x < 0 || rc.y < 0) continue;
        float v = h0c[(size_t)rc.x * 32 + f];
        atomicAdd(&aggm1[(size_t)rc.y * 32 + f], v);
    }
}

// ---- transform layer 1: h1 = relu(sum_r mean_r @ W_r + h0 @ Wroot + b) ----
__global__ void trans1_k(const float* __restrict__ w1r, const float* __restrict__ wroot,
                         const float* __restrict__ b1, const int* __restrict__ nodes1,
                         const int* __restrict__ slot0, const float* __restrict__ h0c,
                         const float* __restrict__ aggm1, const float* __restrict__ cntc,
                         float* __restrict__ h1c, const int* __restrict__ ctr) {
    __shared__ float s_w[NREL * 32 * 64], s_wr[32 * 64], s_b[64];
    int t = threadIdx.x;
    for (int i = t; i < NREL * 32 * 64; i += blockDim.x) s_w[i] = w1r[i];
    for (int i = t; i < 32 * 64; i += blockDim.x) s_wr[i] = wroot[i];
    if (t < 64) s_b[t] = b1[t];
    __syncthreads();
    int f = t & 63;
    int wv  = (blockIdx.x * blockDim.x + t) >> 6;
    int nwv = (gridDim.x * blockDim.x) >> 6;
    int b = wv & (NB - 1);
    int cb = min(ctr[CTR(0, b)], BC1);
    int step = nwv >> 6;
    for (int i = wv >> 6; i < cb; i += step) {
        int j = b * BC1 + i;
        int n = nodes1[j];
        int s0 = slot0[n];
        float acc = s_b[f];
        if (s0 >= 0) {
            const float4* h4 = (const float4*)(h0c + (size_t)s0 * 32);
#pragma unroll
            for (int k4 = 0; k4 < 8; k4++) {
                float4 hv = h4[k4];
                const float* wp = &s_wr[(k4 * 4) * 64 + f];
                acc += hv.x * wp[0] + hv.y * wp[64] + hv.z * wp[128] + hv.w * wp[192];
            }
        }
#pragma unroll
        for (int r = 0; r < NREL; r++) {
            float ci = cntc[j * 4 + r];
            const float4* m4 = (const float4*)(aggm1 + ((size_t)j * 4 + r) * 32);
            float tmp = 0.0f;
#pragma unroll
            for (int k4 = 0; k4 < 8; k4++) {
                float4 mv = m4[k4];
                const float* wp = &s_w[r * 2048 + (k4 * 4) * 64 + f];
                tmp += mv.x * wp[0] + mv.y * wp[64] + mv.z * wp[128] + mv.w * wp[192];
            }
            acc += tmp * ci;
        }
        h1c[(size_t)j * 64 + f] = fmaxf(acc, 0.0f);
    }
}

// ---- resolve layer-2 edges ----
__global__ void resolve2_k(const int* __restrict__ src, const int* __restrict__ dst,
                           const int* __restrict__ et, const int* __restrict__ elist2,
                           const int* __restrict__ slot1, const int* __restrict__ inv_map,
                           const int* __restrict__ ctr, int2* __restrict__ rec2) {
    for (int idx = blockIdx.x * blockDim.x + threadIdx.x; idx < CAPE2;
         idx += gridDim.x * blockDim.x) {
        int b = idx >> 8, i = idx & (BCE2 - 1);
        if (i >= min(ctr[CTR(3, b)], BCE2)) continue;
        int e = elist2[idx];
        int ss = slot1[src[e]];
        int g  = inv_map[dst[e]];
        int row = (g >= 0) ? (g * 4 + et[e]) : -1;
        rec2[idx] = make_int2(ss, row);
    }
}

// ---- accumulate raw h1 into per-(graph,rel) sums ----
__global__ void msg2_acc_k(const int2* __restrict__ rec2, const float* __restrict__ h1c,
                           float* __restrict__ aggm2, const int* __restrict__ ctr) {
    int t = threadIdx.x;
    int f = t & 63;
    int wv  = (blockIdx.x * blockDim.x + t) >> 6;
    int nwv = (gridDim.x * blockDim.x) >> 6;
    int b = wv & (NB - 1);
    int cb = min(ctr[CTR(3, b)], BCE2);
    int step = nwv >> 6;
    for (int i = wv >> 6; i < cb; i += step) {
        int j = b * BCE2 + i;
        int2 rc = rec2[j];
        if (rc.x < 0 || rc.y < 0) continue;
        float v = h1c[(size_t)rc.x * 64 + f];
        atomicAdd(&aggm2[(size_t)rc.y * 64 + f], v);
    }
}

// ---- layer-2 transform + classifier, fused: wave per graph ----
__global__ void fin2cls_k(const int* __restrict__ ptr, const int* __restrict__ slot1,
                          const float* __restrict__ w2r, const float* __restrict__ wroot,
                          const float* __restrict__ b2, const float* __restrict__ cw,
                          const float* __restrict__ cb, const float* __restrict__ cntc,
                          const float* __restrict__ h1c, const float* __restrict__ aggm2,
                          float* __restrict__ out, int G) {
    __shared__ float s_w[NREL * 64 * 64], s_wr[64 * 64], s_cw[640], s_cb[10], s_b[64], s_h2[256];
    int t = threadIdx.x;
    for (int i = t; i < NREL * 64 * 64; i += blockDim.x) s_w[i] = w2r[i];
    for (int i = t; i < 64 * 64; i += blockDim.x) s_wr[i] = wroot[i];
    for (int i = t; i < 640; i += blockDim.x) s_cw[i] = cw[i];
    if (t < 10) s_cb[t] = cb[t];
    if (t < 64) s_b[t] = b2[t];
    __syncthreads();
    int wvl = t >> 6, f = t & 63;
    for (int base = blockIdx.x * 4; base < G; base += gridDim.x * 4) {
        int g = base + wvl;
        if (g < G) {
            int last = ptr[g + 1] - 1;
            int s1 = slot1[last];
            float acc = s_b[f];
            if (s1 >= 0) {
                const float4* h4 = (const float4*)(h1c + (size_t)s1 * 64);
#pragma unroll
                for (int k4 = 0; k4 < 16; k4++) {
                    float4 hv = h4[k4];
                    const float* wp = &s_wr[(k4 * 4) * 64 + f];
                    acc += hv.x * wp[0] + hv.y * wp[64] + hv.z * wp[128] + hv.w * wp[192];
                }
#pragma unroll
                for (int r = 0; r < NREL; r++) {
                    float ci = cntc[s1 * 4 + r];
                    const float4* m4 = (const float4*)(aggm2 + ((size_t)g * 4 + r) * 64);
                    float tmp = 0.0f;
#pragma unroll
                    for (int k4 = 0; k4 < 16; k4++) {
                        float4 mv = m4[k4];
                        const float* wp = &s_w[r * 4096 + (k4 * 4) * 64 + f];
                        tmp += mv.x * wp[0] + mv.y * wp[64] + mv.z * wp[128] + mv.w * wp[192];
                    }
                    acc += tmp * ci;
                }
            }
            s_h2[wvl * 64 + f] = fmaxf(acc, 0.0f);
        }
        __syncthreads();
        if (g < G && f < 10) {
            float acc = s_cb[f];
#pragma unroll
            for (int k = 0; k < 64; k++) acc += s_h2[wvl * 64 + k] * s_cw[k * 10 + f];
            out[g * 10 + f] = acc;
        }
        __syncthreads();
    }
}

static inline size_t rnd(size_t x) { return (x + 255) & ~(size_t)255; }

extern "C" void kernel_launch(void* const* d_in, const int* in_sizes, int n_in,
                              void* d_out, int out_size, void* d_ws, size_t ws_size,
                              hipStream_t stream) {
    const int*   x    = (const int*)d_in[0];
    const int*   ei   = (const int*)d_in[1];
    const int*   et   = (const int*)d_in[2];
    const int*   ptr  = (const int*)d_in[3];
    const float* se   = (const float*)d_in[4];
    const float* ce   = (const float*)d_in[5];
    const float* pw   = (const float*)d_in[6];
    const float* pb   = (const float*)d_in[7];
    const float* w1r  = (const float*)d_in[8];
    const float* w1rt = (const float*)d_in[9];
    const float* b1   = (const float*)d_in[10];
    const float* w2r  = (const float*)d_in[11];
    const float* w2rt = (const float*)d_in[12];
    const float* b2   = (const float*)d_in[13];
    const float* cw   = (const float*)d_in[14];
    const float* cb   = (const float*)d_in[15];
    float* out = (float*)d_out;

    const int nN = in_sizes[0] / 2;   // 500000
    const int nE = in_sizes[2];       // 1000000
    const int G  = in_sizes[3] - 1;   // 5000
    const int nBW = (nN + 31) / 32;   // bitmap words (~15625 -> 62.5 KB)

    const int* src = ei;
    const int* dst = ei + nE;

    // ---- workspace layout: [zero region][0xFF region][uninitialized] ----
    char* p = (char*)d_ws;
    size_t off = 0;
    auto take = [&](size_t bytes) { size_t o = off; off += rnd(bytes); return o; };

    int*      ctr   = (int*)     (p + take(4 * NB * CS * sizeof(int)));
    unsigned* bitL  = (unsigned*)(p + take((size_t)nBW * 4));
    unsigned* bitN1 = (unsigned*)(p + take((size_t)nBW * 4));
    float*    cntc  = (float*)   (p + take((size_t)CAP1 * 4 * 4));
    float*    aggm1 = (float*)   (p + take((size_t)CAP1 * 4 * 32 * 4));  // 16 MB
    float*    aggm2 = (float*)   (p + take((size_t)G * 4 * 64 * 4));     // 5 MB
    size_t zero_bytes = off;
    int*      inv_map = (int*)   (p + take((size_t)nN * 4));
    int*      slot1 = (int*)     (p + take((size_t)nN * 4));
    int*      slot0 = (int*)     (p + take((size_t)nN * 4));
    size_t ff_off = zero_bytes, ff_bytes = off - zero_bytes;
    int*      elist1 = (int*)    (p + take((size_t)CAPE1 * 4));
    int*      elist2 = (int*)    (p + take((size_t)CAPE2 * 4));
    int*      nodes1 = (int*)    (p + take((size_t)CAP1 * 4));
    int*      nodes0 = (int*)    (p + take((size_t)CAP0 * 4));
    int2*     rec1  = (int2*)    (p + take((size_t)CAPE1 * 8));
    int2*     rec2  = (int2*)    (p + take((size_t)CAPE2 * 8));
    float*    h0c   = (float*)   (p + take((size_t)CAP0 * 32 * 4));      // 16 MB
    float*    h1c   = (float*)   (p + take((size_t)CAP1 * 64 * 4));      // 8 MB
    // total ~55 MB

    hipMemsetAsync(p, 0, zero_bytes, stream);
    hipMemsetAsync(p + ff_off, 0xFF, ff_bytes, stream);   // inv_map/slot1/slot0 = -1

    int nT = (nE + 3) / 4;
    mark_last_k<<<(G + 255) / 256, 256, 0, stream>>>(ptr, inv_map, bitL, bitN1, slot1, slot0,
                                                     nodes1, nodes0, ctr, G);
    edge_pass1_k<<<(nT + 255) / 256, 256, 0, stream>>>(src, dst, bitL, bitN1, slot1, slot0,
                                                       nodes1, nodes0, elist2, ctr, nE);
    edge_pass2_k<<<(nT + 255) / 256, 256, 0, stream>>>(src, dst, et, bitN1, slot1, slot0,
                                                       nodes0, elist1, cntc, ctr, nE);
    inv_k<<<(CAP1 * 4 + 255) / 256, 256, 0, stream>>>(cntc, CAP1 * 4);
    h0_k<<<512, 256, 0, stream>>>(x, se, ce, pw, pb, nodes0, ctr, h0c);
    resolve1_k<<<512, 256, 0, stream>>>(src, dst, et, elist1, slot0, slot1, ctr, rec1);
    msg1_acc_k<<<1024, 256, 0, stream>>>(rec1, h0c, aggm1, ctr);
    trans1_k<<<256, 256, 0, stream>>>(w1r, w1rt, b1, nodes1, slot0, h0c, aggm1, cntc, h1c, ctr);
    resolve2_k<<<64, 256, 0, stream>>>(src, dst, et, elist2, slot1, inv_map, ctr, rec2);
    msg2_acc_k<<<512, 256, 0, stream>>>(rec2, h1c, aggm2, ctr);
    fin2cls_k<<<128, 256, 0, stream>>>(ptr, slot1, w2r, w2rt, b2, cw, cb, cntc, h1c, aggm2, out, G);
}

// Round 6
// 266.366 us; speedup vs baseline: 1.1870x; 1.1870x over previous
//
#include <hip/hip_runtime.h>

#define NREL 3
#define NB    64            // buckets per push-list
#define CS    16            // ints per bucket counter (64 B line each)
#define CAP0  131072        // nodes needing h0  (expected ~45K)
#define CAP1  32768         // nodes needing h1  (expected ~15K, bound 5000+CAPE2)
#define CAPE1 65536         // layer-1 relevant edges (expected ~30K +- 0.2K)
#define CAPE2 16384         // layer-2 relevant edges (expected ~10K +- 0.1K)
#define BC0   (CAP0 / NB)   // 2048 (shift 11)
#define BC1   (CAP1 / NB)   // 512  (shift 9)
#define BCE1  (CAPE1 / NB)  // 1024 (shift 10)
#define BCE2  (CAPE2 / NB)  // 256  (shift 8)
// ctr: 4 lists x 64 buckets x 16 ints. list 0=nodes1, 1=nodes0, 2=elist1, 3=elist2
#define CTR(list, b) ((list) * NB * CS + (b) * CS)

__device__ __forceinline__ int bittest(const unsigned* bm, int n) {
    return (bm[n >> 5] >> (n & 31)) & 1u;
}

__device__ __forceinline__ void claim_node(int n, int* __restrict__ slot,
                                           int* __restrict__ nodes,
                                           int* __restrict__ ctr, int list,
                                           int bcap, int bucket) {
    if (atomicCAS(&slot[n], -1, -2) == -1) {
        int p = atomicAdd(&ctr[CTR(list, bucket)], 1);
        if (p < bcap) {
            int sl = bucket * bcap + p;
            nodes[sl] = n;
            atomicExch(&slot[n], sl);
        }
    }
}

// ---- per graph: mark last node, claim its h1/h0 slots ----
__global__ void mark_last_k(const int* __restrict__ ptr, int* __restrict__ inv_map,
                            unsigned* __restrict__ bitL, unsigned* __restrict__ bitN1,
                            int* __restrict__ slot1, int* __restrict__ slot0,
                            int* __restrict__ nodes1, int* __restrict__ nodes0,
                            int* __restrict__ ctr, int G) {
    int g = blockIdx.x * blockDim.x + threadIdx.x;
    if (g >= G) return;
    int bucket = g & (NB - 1);
    int last = ptr[g + 1] - 1;
    inv_map[last] = g;
    atomicOr(&bitL[last >> 5], 1u << (last & 31));
    atomicOr(&bitN1[last >> 5], 1u << (last & 31));
    claim_node(last, slot1, nodes1, ctr, 0, BC1, bucket);
    claim_node(last, slot0, nodes0, ctr, 1, BC0, bucket);
}

// ---- scan edges: dst is last node -> elist2; src joins need1 (+h0) ----
__global__ void edge_pass1_k(const int* __restrict__ src, const int* __restrict__ dst,
                             const unsigned* __restrict__ bitL, unsigned* __restrict__ bitN1,
                             int* __restrict__ slot1, int* __restrict__ slot0,
                             int* __restrict__ nodes1, int* __restrict__ nodes0,
                             int* __restrict__ elist2, int* __restrict__ ctr, int nE) {
    int t = blockIdx.x * blockDim.x + threadIdx.x;
    int bucket = (t >> 6) & (NB - 1);
    int e0 = t * 4;
    if (e0 >= nE) return;
    int d[4];
    int cnt = min(4, nE - e0);
    if (cnt == 4) { int4 v = *(const int4*)(dst + e0); d[0]=v.x; d[1]=v.y; d[2]=v.z; d[3]=v.w; }
    else for (int k = 0; k < cnt; k++) d[k] = dst[e0 + k];
#pragma unroll
    for (int k = 0; k < 4; k++) {
        if (k >= cnt) break;
        if (bittest(bitL, d[k])) {
            int e = e0 + k;
            int p = atomicAdd(&ctr[CTR(3, bucket)], 1);
            if (p < BCE2) elist2[bucket * BCE2 + p] = e;
            int s = src[e];
            atomicOr(&bitN1[s >> 5], 1u << (s & 31));
            claim_node(s, slot1, nodes1, ctr, 0, BC1, bucket);
            claim_node(s, slot0, nodes0, ctr, 1, BC0, bucket);
        }
    }
}

// ---- scan edges: dst in need1 -> elist1 + per-(slot,rel) counts; src joins h0 set ----
__global__ void edge_pass2_k(const int* __restrict__ src, const int* __restrict__ dst,
                             const int* __restrict__ et, const unsigned* __restrict__ bitN1,
                             const int* __restrict__ slot1, int* __restrict__ slot0,
                             int* __restrict__ nodes0, int* __restrict__ elist1,
                             float* __restrict__ cntc, int* __restrict__ ctr, int nE) {
    int t = blockIdx.x * blockDim.x + threadIdx.x;
    int bucket = (t >> 6) & (NB - 1);
    int e0 = t * 4;
    if (e0 >= nE) return;
    int d[4];
    int cnt = min(4, nE - e0);
    if (cnt == 4) { int4 v = *(const int4*)(dst + e0); d[0]=v.x; d[1]=v.y; d[2]=v.z; d[3]=v.w; }
    else for (int k = 0; k < cnt; k++) d[k] = dst[e0 + k];
#pragma unroll
    for (int k = 0; k < 4; k++) {
        if (k >= cnt) break;
        if (bittest(bitN1, d[k])) {
            int e = e0 + k;
            int s1 = slot1[d[k]];                 // hit path only (~3% of edges)
            if (s1 >= 0) {
                int p = atomicAdd(&ctr[CTR(2, bucket)], 1);
                if (p < BCE1) elist1[bucket * BCE1 + p] = e;
                atomicAdd(&cntc[s1 * 4 + et[e]], 1.0f);
                claim_node(src[e], slot0, nodes0, ctr, 1, BC0, bucket);
            }
        }
    }
}

// ---- embed + pre-linear + relu for claimed h0 slots (linear slot sweep) ----
__global__ void h0_k(const int* __restrict__ x, const float* __restrict__ se,
                     const float* __restrict__ ce, const float* __restrict__ pw,
                     const float* __restrict__ pb, const int* __restrict__ nodes0,
                     const int* __restrict__ ctr, float* __restrict__ h0c) {
    __shared__ float s_se[128], s_ce[128], s_pw[512], s_pb[32];
    int t = threadIdx.x;
    if (t < 128) { s_se[t] = se[t]; s_ce[t] = ce[t]; }
    if (t < 32)  s_pb[t] = pb[t];
    for (int i = t; i < 512; i += 256) s_pw[i] = pw[i];
    __syncthreads();
    int lane = t & 63, f = lane & 31, half = lane >> 5;
    int wv  = (blockIdx.x * blockDim.x + t) >> 6;
    int nwv = (gridDim.x * blockDim.x) >> 6;
    for (int idx = wv * 2 + half; idx < CAP0; idx += nwv * 2) {
        int b = idx >> 11, i = idx & (BC0 - 1);
        if (i >= min(ctr[CTR(1, b)], BC0)) continue;
        int n = nodes0[idx];
        int x0 = x[n * 2], x1 = x[n * 2 + 1];
        float acc = s_pb[f];
#pragma unroll
        for (int k = 0; k < 8; k++) acc += s_se[x0 * 8 + k] * s_pw[k * 32 + f];
#pragma unroll
        for (int k = 0; k < 8; k++) acc += s_ce[x1 * 8 + k] * s_pw[(k + 8) * 32 + f];
        h0c[(size_t)idx * 32 + f] = fmaxf(acc, 0.0f);
    }
}

// ---- layer-1 accumulate: raw h0[src] summed into per-(slot1,rel) rows ----
// half-wave per edge, f = lane&31. No LDS, no weights -> huge grid, pure MLP.
__global__ void msg1_k(const int* __restrict__ src, const int* __restrict__ dst,
                       const int* __restrict__ et, const int* __restrict__ elist1,
                       const int* __restrict__ slot0, const int* __restrict__ slot1,
                       const float* __restrict__ h0c, float* __restrict__ aggm1,
                       const int* __restrict__ ctr) {
    int t = threadIdx.x;
    int lane = t & 63, f = lane & 31, half = lane >> 5;
    int wv  = (blockIdx.x * blockDim.x + t) >> 6;
    int nwv = (gridDim.x * blockDim.x) >> 6;
    for (int idx = wv * 2 + half; idx < CAPE1; idx += nwv * 2) {
        int b = idx >> 10, i = idx & (BCE1 - 1);
        if (i >= min(ctr[CTR(2, b)], BCE1)) continue;
        int e = elist1[idx];
        int s0 = slot0[src[e]];
        int s1 = slot1[dst[e]];
        int r  = et[e];
        if (s0 < 0 || s1 < 0) continue;
        float v = h0c[(size_t)s0 * 32 + f];
        atomicAdd(&aggm1[((size_t)s1 * 4 + r) * 32 + f], v);
    }
}

// ---- transform layer 1: h1 = relu(sum_r (sum_r_row/cnt) @ W_r + h0 @ Wroot + b) ----
__global__ void trans1_k(const float* __restrict__ w1r, const float* __restrict__ wroot,
                         const float* __restrict__ b1, const int* __restrict__ nodes1,
                         const int* __restrict__ slot0, const float* __restrict__ h0c,
                         const float* __restrict__ aggm1, const float* __restrict__ cntc,
                         float* __restrict__ h1c, const int* __restrict__ ctr) {
    __shared__ float s_w[NREL * 32 * 64], s_wr[32 * 64], s_b[64];
    int t = threadIdx.x;
    for (int i = t; i < NREL * 32 * 64; i += blockDim.x) s_w[i] = w1r[i];
    for (int i = t; i < 32 * 64; i += blockDim.x) s_wr[i] = wroot[i];
    if (t < 64) s_b[t] = b1[t];
    __syncthreads();
    int f = t & 63;
    int wv  = (blockIdx.x * blockDim.x + t) >> 6;
    int nwv = (gridDim.x * blockDim.x) >> 6;
    for (int j = wv; j < CAP1; j += nwv) {
        int b = j >> 9, i = j & (BC1 - 1);
        if (i >= min(ctr[CTR(0, b)], BC1)) continue;
        int n = nodes1[j];
        int s0 = slot0[n];
        float acc = s_b[f];
        if (s0 >= 0) {
            const float4* h4 = (const float4*)(h0c + (size_t)s0 * 32);
#pragma unroll
            for (int k4 = 0; k4 < 8; k4++) {
                float4 hv = h4[k4];
                const float* wp = &s_wr[(k4 * 4) * 64 + f];
                acc += hv.x * wp[0] + hv.y * wp[64] + hv.z * wp[128] + hv.w * wp[192];
            }
        }
#pragma unroll
        for (int r = 0; r < NREL; r++) {
            float ci = 1.0f / fmaxf(cntc[j * 4 + r], 1.0f);
            const float4* m4 = (const float4*)(aggm1 + ((size_t)j * 4 + r) * 32);
            float tmp = 0.0f;
#pragma unroll
            for (int k4 = 0; k4 < 8; k4++) {
                float4 mv = m4[k4];
                const float* wp = &s_w[r * 2048 + (k4 * 4) * 64 + f];
                tmp += mv.x * wp[0] + mv.y * wp[64] + mv.z * wp[128] + mv.w * wp[192];
            }
            acc += tmp * ci;
        }
        h1c[(size_t)j * 64 + f] = fmaxf(acc, 0.0f);
    }
}

// ---- layer-2 accumulate: raw h1[src] summed into per-(graph,rel) rows ----
__global__ void msg2_k(const int* __restrict__ src, const int* __restrict__ dst,
                       const int* __restrict__ et, const int* __restrict__ elist2,
                       const int* __restrict__ slot1, const int* __restrict__ inv_map,
                       const float* __restrict__ h1c, float* __restrict__ aggm2,
                       const int* __restrict__ ctr) {
    int t = threadIdx.x;
    int f = t & 63;
    int wv  = (blockIdx.x * blockDim.x + t) >> 6;
    int nwv = (gridDim.x * blockDim.x) >> 6;
    for (int idx = wv; idx < CAPE2; idx += nwv) {
        int b = idx >> 8, i = idx & (BCE2 - 1);
        if (i >= min(ctr[CTR(3, b)], BCE2)) continue;
        int e = elist2[idx];
        int ss = slot1[src[e]];
        int g  = inv_map[dst[e]];
        int r  = et[e];
        if (ss < 0 || g < 0) continue;
        float v = h1c[(size_t)ss * 64 + f];
        atomicAdd(&aggm2[((size_t)g * 4 + r) * 64 + f], v);
    }
}

// ---- layer-2 transform + classifier, fused: wave per graph ----
__global__ void fin2cls_k(const int* __restrict__ ptr, const int* __restrict__ slot1,
                          const float* __restrict__ w2r, const float* __restrict__ wroot,
                          const float* __restrict__ b2, const float* __restrict__ cw,
                          const float* __restrict__ cb, const float* __restrict__ cntc,
                          const float* __restrict__ h1c, const float* __restrict__ aggm2,
                          float* __restrict__ out, int G) {
    __shared__ float s_w[NREL * 64 * 64], s_wr[64 * 64], s_cw[640], s_cb[10], s_b[64], s_h2[256];
    int t = threadIdx.x;
    for (int i = t; i < NREL * 64 * 64; i += blockDim.x) s_w[i] = w2r[i];
    for (int i = t; i < 64 * 64; i += blockDim.x) s_wr[i] = wroot[i];
    for (int i = t; i < 640; i += blockDim.x) s_cw[i] = cw[i];
    if (t < 10) s_cb[t] = cb[t];
    if (t < 64) s_b[t] = b2[t];
    __syncthreads();
    int wvl = t >> 6, f = t & 63;
    for (int base = blockIdx.x * 4; base < G; base += gridDim.x * 4) {
        int g = base + wvl;
        if (g < G) {
            int last = ptr[g + 1] - 1;
            int s1 = slot1[last];
            float acc = s_b[f];
            if (s1 >= 0) {
                const float4* h4 = (const float4*)(h1c + (size_t)s1 * 64);
#pragma unroll
                for (int k4 = 0; k4 < 16; k4++) {
                    float4 hv = h4[k4];
                    const float* wp = &s_wr[(k4 * 4) * 64 + f];
                    acc += hv.x * wp[0] + hv.y * wp[64] + hv.z * wp[128] + hv.w * wp[192];
                }
#pragma unroll
                for (int r = 0; r < NREL; r++) {
                    float ci = 1.0f / fmaxf(cntc[s1 * 4 + r], 1.0f);
                    const float4* m4 = (const float4*)(aggm2 + ((size_t)g * 4 + r) * 64);
                    float tmp = 0.0f;
#pragma unroll
                    for (int k4 = 0; k4 < 16; k4++) {
                        float4 mv = m4[k4];
                        const float* wp = &s_w[r * 4096 + (k4 * 4) * 64 + f];
                        tmp += mv.x * wp[0] + mv.y * wp[64] + mv.z * wp[128] + mv.w * wp[192];
                    }
                    acc += tmp * ci;
                }
            }
            s_h2[wvl * 64 + f] = fmaxf(acc, 0.0f);
        }
        __syncthreads();
        if (g < G && f < 10) {
            float acc = s_cb[f];
#pragma unroll
            for (int k = 0; k < 64; k++) acc += s_h2[wvl * 64 + k] * s_cw[k * 10 + f];
            out[g * 10 + f] = acc;
        }
        __syncthreads();
    }
}

static inline size_t rnd(size_t x) { return (x + 255) & ~(size_t)255; }

extern "C" void kernel_launch(void* const* d_in, const int* in_sizes, int n_in,
                              void* d_out, int out_size, void* d_ws, size_t ws_size,
                              hipStream_t stream) {
    const int*   x    = (const int*)d_in[0];
    const int*   ei   = (const int*)d_in[1];
    const int*   et   = (const int*)d_in[2];
    const int*   ptr  = (const int*)d_in[3];
    const float* se   = (const float*)d_in[4];
    const float* ce   = (const float*)d_in[5];
    const float* pw   = (const float*)d_in[6];
    const float* pb   = (const float*)d_in[7];
    const float* w1r  = (const float*)d_in[8];
    const float* w1rt = (const float*)d_in[9];
    const float* b1   = (const float*)d_in[10];
    const float* w2r  = (const float*)d_in[11];
    const float* w2rt = (const float*)d_in[12];
    const float* b2   = (const float*)d_in[13];
    const float* cw   = (const float*)d_in[14];
    const float* cb   = (const float*)d_in[15];
    float* out = (float*)d_out;

    const int nN = in_sizes[0] / 2;   // 500000
    const int nE = in_sizes[2];       // 1000000
    const int G  = in_sizes[3] - 1;   // 5000
    const int nBW = (nN + 31) / 32;   // bitmap words (~15625 -> 62.5 KB)

    const int* src = ei;
    const int* dst = ei + nE;

    // ---- workspace layout: [zero region][0xFF region][uninitialized] ----
    char* p = (char*)d_ws;
    size_t off = 0;
    auto take = [&](size_t bytes) { size_t o = off; off += rnd(bytes); return o; };

    int*      ctr   = (int*)     (p + take(4 * NB * CS * sizeof(int)));
    unsigned* bitL  = (unsigned*)(p + take((size_t)nBW * 4));
    unsigned* bitN1 = (unsigned*)(p + take((size_t)nBW * 4));
    float*    cntc  = (float*)   (p + take((size_t)CAP1 * 4 * 4));
    float*    aggm1 = (float*)   (p + take((size_t)CAP1 * 4 * 32 * 4));  // 16 MB
    float*    aggm2 = (float*)   (p + take((size_t)G * 4 * 64 * 4));     // 5 MB
    size_t zero_bytes = off;
    int*      inv_map = (int*)   (p + take((size_t)nN * 4));
    int*      slot1 = (int*)     (p + take((size_t)nN * 4));
    int*      slot0 = (int*)     (p + take((size_t)nN * 4));
    size_t ff_off = zero_bytes, ff_bytes = off - zero_bytes;
    int*      elist1 = (int*)    (p + take((size_t)CAPE1 * 4));
    int*      elist2 = (int*)    (p + take((size_t)CAPE2 * 4));
    int*      nodes1 = (int*)    (p + take((size_t)CAP1 * 4));
    int*      nodes0 = (int*)    (p + take((size_t)CAP0 * 4));
    float*    h0c   = (float*)   (p + take((size_t)CAP0 * 32 * 4));      // 16 MB
    float*    h1c   = (float*)   (p + take((size_t)CAP1 * 64 * 4));      // 8 MB
    // total ~53 MB

    hipMemsetAsync(p, 0, zero_bytes, stream);
    hipMemsetAsync(p + ff_off, 0xFF, ff_bytes, stream);   // inv_map/slot1/slot0 = -1

    int nT = (nE + 3) / 4;
    mark_last_k<<<(G + 255) / 256, 256, 0, stream>>>(ptr, inv_map, bitL, bitN1, slot1, slot0,
                                                     nodes1, nodes0, ctr, G);
    edge_pass1_k<<<(nT + 255) / 256, 256, 0, stream>>>(src, dst, bitL, bitN1, slot1, slot0,
                                                       nodes1, nodes0, elist2, ctr, nE);
    edge_pass2_k<<<(nT + 255) / 256, 256, 0, stream>>>(src, dst, et, bitN1, slot1, slot0,
                                                       nodes0, elist1, cntc, ctr, nE);
    h0_k<<<1024, 256, 0, stream>>>(x, se, ce, pw, pb, nodes0, ctr, h0c);
    msg1_k<<<2048, 256, 0, stream>>>(src, dst, et, elist1, slot0, slot1, h0c, aggm1, ctr);
    trans1_k<<<1024, 256, 0, stream>>>(w1r, w1rt, b1, nodes1, slot0, h0c, aggm1, cntc, h1c, ctr);
    msg2_k<<<512, 256, 0, stream>>>(src, dst, et, elist2, slot1, inv_map, h1c, aggm2, ctr);
    fin2cls_k<<<512, 256, 0, stream>>>(ptr, slot1, w2r, w2rt, b2, cw, cb, cntc, h1c, aggm2, out, G);
}